// Round 2
// baseline (242.037 us; speedup 1.0000x reference)
//
#include <hip/hip_runtime.h>

#define K_DIM   4096
#define N_DIM   4096
#define M_ROWS  8192

// ---------------------------------------------------------------------------
// Kernel 1: transpose B [4096][16] -> Bt [16][4096]  (256 KB, one-shot)
__global__ __launch_bounds__(256) void transpose_B(const float* __restrict__ B,
                                                   float* __restrict__ Bt) {
    const int i = blockIdx.x * 256 + threadIdx.x;       // 0 .. 65535
    const int r = i >> 12;                              // 0..15
    const int c = i & (N_DIM - 1);                      // 0..4095
    Bt[i] = B[c * 16 + r];
}

// ---------------------------------------------------------------------------
// Fused LoRA: per block of 8 rows:
//   phase 1: t[8][16] = x_rows @ A^T   (lanes parallel along K, coalesced)
//   reduce via padded LDS transpose
//   phase 2: out_rows = t @ B^T        (coalesced Bt loads, 1KB stores)
__global__ __launch_bounds__(128, 2) void lora_fused(const float* __restrict__ x,
                                                     const float* __restrict__ A,
                                                     const float* __restrict__ Bt,
                                                     float* __restrict__ out) {
    __shared__ float red[128 * 65];     // 33,280 B, pad 65 -> conflict-free
    __shared__ float t_s[128];          // t tile: 8 rows x 16

    const int tid  = threadIdx.x;       // 0..127
    const int wv   = tid >> 6;          // k-half owned by this wave
    const int lane = tid & 63;
    const int kl   = lane & 31;         // k-lane within half-wave
    const int rh   = lane >> 5;         // row-half (rows 0-3 vs 4-7)
    const int row0 = blockIdx.x * 8;

    const float4* x4 = (const float4*)x;
    const float4* A4 = (const float4*)A;

    // ---- phase 1: acc[j][r] = partial dot over this lane's k positions ----
    float acc[4][16];
    #pragma unroll
    for (int j = 0; j < 4; ++j)
        #pragma unroll
        for (int r = 0; r < 16; ++r) acc[j][r] = 0.f;

    for (int it = 0; it < 16; ++it) {
        const int kf = wv * 512 + it * 32 + kl;   // float4 index in row
        float4 xv[4];
        #pragma unroll
        for (int j = 0; j < 4; ++j)
            xv[j] = x4[(row0 + rh * 4 + j) * (K_DIM / 4) + kf];
        #pragma unroll
        for (int r = 0; r < 16; ++r) {
            const float4 av = A4[r * (K_DIM / 4) + kf];
            #pragma unroll
            for (int j = 0; j < 4; ++j) {
                acc[j][r] = fmaf(xv[j].x, av.x, acc[j][r]);
                acc[j][r] = fmaf(xv[j].y, av.y, acc[j][r]);
                acc[j][r] = fmaf(xv[j].z, av.z, acc[j][r]);
                acc[j][r] = fmaf(xv[j].w, av.w, acc[j][r]);
            }
        }
    }

    // ---- reduce: red[tid][v], v = j*16 + r ----
    #pragma unroll
    for (int j = 0; j < 4; ++j)
        #pragma unroll
        for (int r = 0; r < 16; ++r)
            red[tid * 65 + j * 16 + r] = acc[j][r];
    __syncthreads();

    {
        // output o = tid: rh_o = tid>>6, v = tid&63
        // t[rh_o*4 + (v>>4)][v&15] = sum over both waves, 32 k-lanes of matching rh
        const int v   = tid & 63;
        const int rho = tid >> 6;
        float s = 0.f;
        #pragma unroll
        for (int w = 0; w < 2; ++w) {
            #pragma unroll
            for (int i = 0; i < 32; ++i)
                s += red[(w * 64 + rho * 32 + i) * 65 + v];
        }
        t_s[tid] = s;   // t_s index == row*16 + r == tid by construction
    }
    __syncthreads();

    // ---- phase 2: out[row0+row][:] = t[row][:] @ Bt ----
    float4 tq[8][4];
    #pragma unroll
    for (int row = 0; row < 8; ++row)
        #pragma unroll
        for (int q = 0; q < 4; ++q)
            tq[row][q] = *(const float4*)&t_s[row * 16 + q * 4];  // broadcast

    const float4* Bt4 = (const float4*)Bt;
    float4* out4 = (float4*)out;

    for (int ch = 0; ch < 8; ++ch) {
        const int c4 = ch * 128 + tid;            // float4 column index
        float4 bv[16];
        #pragma unroll
        for (int r = 0; r < 16; ++r)
            bv[r] = Bt4[r * (N_DIM / 4) + c4];    // 1KB contiguous per instr
        #pragma unroll
        for (int row = 0; row < 8; ++row) {
            float4 o = {0.f, 0.f, 0.f, 0.f};
            #pragma unroll
            for (int r = 0; r < 16; ++r) {
                const float4 tv4 = tq[row][r >> 2];
                const float tv = ((r & 3) == 0) ? tv4.x :
                                 ((r & 3) == 1) ? tv4.y :
                                 ((r & 3) == 2) ? tv4.z : tv4.w;
                o.x = fmaf(tv, bv[r].x, o.x);
                o.y = fmaf(tv, bv[r].y, o.y);
                o.z = fmaf(tv, bv[r].z, o.z);
                o.w = fmaf(tv, bv[r].w, o.w);
            }
            out4[(size_t)(row0 + row) * (N_DIM / 4) + c4] = o;
        }
    }
}

extern "C" void kernel_launch(void* const* d_in, const int* in_sizes, int n_in,
                              void* d_out, int out_size, void* d_ws, size_t ws_size,
                              hipStream_t stream) {
    const float* x = (const float*)d_in[0];            // [4,2048,4096]
    const float* B = (const float*)d_in[1];            // [4096,16]
    const float* A = (const float*)d_in[2];            // [16,4096]
    float* out = (float*)d_out;                        // [4,2048,4096]
    float* Bt  = (float*)d_ws;                         // [16,4096] scratch

    transpose_B<<<(N_DIM * 16) / 256, 256, 0, stream>>>(B, Bt);
    lora_fused<<<M_ROWS / 8, 128, 0, stream>>>(x, A, Bt, out);
}

// Round 3
// 81.311 us; speedup vs baseline: 2.9767x; 2.9767x over previous
//
#include <hip/hip_runtime.h>

#define K_DIM   4096
#define N_DIM   4096
#define M_ROWS  8192
#define KF      (K_DIM / 4)    // 1024 float4 per row
#define NF      (N_DIM / 4)    // 1024 float4 per row

// ---------------------------------------------------------------------------
// Kernel 1: transpose B [4096][16] -> Bt [16][4096]  (256 KB, one-shot)
__global__ __launch_bounds__(256) void transpose_B(const float* __restrict__ B,
                                                   float* __restrict__ Bt) {
    const int i = blockIdx.x * 256 + threadIdx.x;       // 0 .. 65535
    const int r = i >> 12;                              // 0..15
    const int c = i & (N_DIM - 1);                      // 0..4095
    Bt[i] = B[c * 16 + r];
}

// ---------------------------------------------------------------------------
// Fused LoRA, one wave (64 threads) per block, 4 rows per wave.
// Phase 1: acc[j*16+r] = dot(x[row0+j], A[r]) over this lane's k-slice.
//          Lanes run along K: every load is a 1KB contiguous wave burst.
// Reduce:  value-halving shfl_xor butterfly (63 shuffles, no LDS).
//          After 6 steps lane l holds t[row0 + (l>>4)][l & 15].
// Phase 2: broadcast t into tv[4][16], stream Bt chunks, coalesced stores.
__global__ __launch_bounds__(64, 2) void lora_fused(const float* __restrict__ x,
                                                    const float* __restrict__ A,
                                                    const float* __restrict__ Bt,
                                                    float* __restrict__ out) {
    const int lane = threadIdx.x;        // 0..63 (one wave)
    const int row0 = blockIdx.x * 4;

    const float4* x4  = (const float4*)x;
    const float4* A4  = (const float4*)A;

    // ---- phase 1 ----
    float red[64];
    #pragma unroll
    for (int v = 0; v < 64; ++v) red[v] = 0.f;

    for (int it = 0; it < 16; ++it) {
        const int kf = it * 64 + lane;   // float4 index within a row
        float4 xv[4];
        #pragma unroll
        for (int j = 0; j < 4; ++j)
            xv[j] = x4[(size_t)(row0 + j) * KF + kf];
        #pragma unroll
        for (int r = 0; r < 16; ++r) {
            const float4 av = A4[r * KF + kf];
            #pragma unroll
            for (int j = 0; j < 4; ++j) {
                float a = red[j * 16 + r];
                a = fmaf(xv[j].x, av.x, a);
                a = fmaf(xv[j].y, av.y, a);
                a = fmaf(xv[j].z, av.z, a);
                a = fmaf(xv[j].w, av.w, a);
                red[j * 16 + r] = a;
            }
        }
    }

    // ---- cross-lane reduce: lane l ends with sum over lanes of red[l] ----
    #pragma unroll
    for (int s = 0; s < 6; ++s) {
        const int m = 1 << s;
        const int b = (lane >> s) & 1;
        #pragma unroll
        for (int u = 0; u < (64 >> (s + 1)); ++u) {
            const float lo = red[2 * u];
            const float hi = red[2 * u + 1];
            const float send = b ? lo : hi;
            const float recv = __shfl_xor(send, m, 64);
            const float kept = b ? hi : lo;
            red[u] = kept + recv;
        }
    }
    const float t_val = red[0];          // t[row0 + (lane>>4)][lane&15]

    // ---- broadcast t tile to all lanes ----
    float tv[4][16];
    #pragma unroll
    for (int j = 0; j < 4; ++j)
        #pragma unroll
        for (int r = 0; r < 16; ++r)
            tv[j][r] = __shfl(t_val, j * 16 + r, 64);

    // ---- phase 2: out[row0+j][:] = tv[j][:] @ Bt ----
    const float4* Bt4 = (const float4*)Bt;
    float4* out4 = (float4*)out;

    for (int ch = 0; ch < 16; ++ch) {
        const int c4 = ch * 64 + lane;   // float4 column index
        float4 bv[16];
        #pragma unroll
        for (int r = 0; r < 16; ++r)
            bv[r] = Bt4[r * NF + c4];    // 1KB contiguous per instr (L2-hot)
        #pragma unroll
        for (int j = 0; j < 4; ++j) {
            float4 o = {0.f, 0.f, 0.f, 0.f};
            #pragma unroll
            for (int r = 0; r < 16; ++r) {
                const float tj = tv[j][r];
                o.x = fmaf(tj, bv[r].x, o.x);
                o.y = fmaf(tj, bv[r].y, o.y);
                o.z = fmaf(tj, bv[r].z, o.z);
                o.w = fmaf(tj, bv[r].w, o.w);
            }
            out4[(size_t)(row0 + j) * NF + c4] = o;
        }
    }
}

extern "C" void kernel_launch(void* const* d_in, const int* in_sizes, int n_in,
                              void* d_out, int out_size, void* d_ws, size_t ws_size,
                              hipStream_t stream) {
    const float* x = (const float*)d_in[0];            // [4,2048,4096]
    const float* B = (const float*)d_in[1];            // [4096,16]
    const float* A = (const float*)d_in[2];            // [16,4096]
    float* out = (float*)d_out;                        // [4,2048,4096]
    float* Bt  = (float*)d_ws;                         // [16,4096] scratch

    transpose_B<<<(N_DIM * 16) / 256, 256, 0, stream>>>(B, Bt);
    lora_fused<<<M_ROWS / 4, 64, 0, stream>>>(x, A, Bt, out);
}

// Round 4
// 77.286 us; speedup vs baseline: 3.1317x; 1.0521x over previous
//
#include <hip/hip_runtime.h>

#define K_DIM   4096
#define N_DIM   4096
#define M_ROWS  8192
#define KF      (K_DIM / 4)    // 1024 float4 per x/A row
#define NF      (N_DIM / 4)    // 1024 float4 per out/Bt row
#define KSPLIT  4
#define TPART_F4_STRIDE (M_ROWS * 16 / 4)   // float4 stride per k-partial

// ---------------------------------------------------------------------------
// Kernel 1: transpose B [4096][16] -> Bt [16][4096]  (256 KB, one-shot)
__global__ __launch_bounds__(256) void transpose_B(const float* __restrict__ B,
                                                   float* __restrict__ Bt) {
    const int i = blockIdx.x * 256 + threadIdx.x;       // 0 .. 65535
    const int r = i >> 12;                              // 0..15
    const int c = i & (N_DIM - 1);                      // 0..4095
    Bt[i] = B[c * 16 + r];
}

// ---------------------------------------------------------------------------
// Kernel 2: t partials. Block = 4 waves x 4 rows = 16 rows, K quarter.
// Per wave: acc[j*16+r] over its K-quarter, lanes along K (1KB bursts),
// then in-wave butterfly -> lane l holds partial t[row0+(l>>4)][l&15].
__global__ __launch_bounds__(256, 4) void lora_xat(const float* __restrict__ x,
                                                   const float* __restrict__ A,
                                                   float* __restrict__ tpart) {
    const int tid  = threadIdx.x;
    const int wv   = tid >> 6;            // wave -> 4-row group
    const int lane = tid & 63;
    const int rb   = blockIdx.x >> 2;     // 16-row tile
    const int h    = blockIdx.x & 3;      // K quarter
    const int row0 = rb * 16 + wv * 4;
    const int kbase = h * 256;            // float4 units (1024/4)

    const float4* x4 = (const float4*)x;
    const float4* A4 = (const float4*)A;

    float red[64];
    #pragma unroll
    for (int v = 0; v < 64; ++v) red[v] = 0.f;

    for (int it = 0; it < 4; ++it) {
        const int kf = kbase + it * 64 + lane;
        float4 xv[4];
        #pragma unroll
        for (int j = 0; j < 4; ++j)
            xv[j] = x4[(size_t)(row0 + j) * KF + kf];
        #pragma unroll
        for (int r = 0; r < 16; ++r) {
            const float4 av = A4[r * KF + kf];
            #pragma unroll
            for (int j = 0; j < 4; ++j) {
                float a = red[j * 16 + r];
                a = fmaf(xv[j].x, av.x, a);
                a = fmaf(xv[j].y, av.y, a);
                a = fmaf(xv[j].z, av.z, a);
                a = fmaf(xv[j].w, av.w, a);
                red[j * 16 + r] = a;
            }
        }
    }

    // in-wave butterfly: lane l ends with sum over lanes of red[l]
    #pragma unroll
    for (int s = 0; s < 6; ++s) {
        const int m = 1 << s;
        const int b = (lane >> s) & 1;
        #pragma unroll
        for (int u = 0; u < (64 >> (s + 1)); ++u) {
            const float lo = red[2 * u];
            const float hi = red[2 * u + 1];
            const float send = b ? lo : hi;
            const float recv = __shfl_xor(send, m, 64);
            const float kept = b ? hi : lo;
            red[u] = kept + recv;
        }
    }

    // contiguous 256B store per wave: tpart[h][row0 + (lane>>4)][lane&15]
    tpart[((size_t)h * M_ROWS + row0) * 16 + lane] = red[0];
}

// ---------------------------------------------------------------------------
// Kernel 3: out = t @ B^T. Block = 16 rows x 1024 cols, 256 threads.
// Thread owns one float4 column group across all 16 rows; B rows live in
// bv[16] registers; t tile broadcast from 1KB LDS.
__global__ __launch_bounds__(256, 4) void lora_tb(const float* __restrict__ tpart,
                                                  const float* __restrict__ Bt,
                                                  float* __restrict__ out) {
    const int tid = threadIdx.x;
    const int rb  = blockIdx.x >> 2;      // 16-row tile
    const int cb  = blockIdx.x & 3;       // 1024-col chunk

    __shared__ float4 t_s4[64];           // 16 rows x 16 r
    if (tid < 64) {
        const float4* p4 = (const float4*)tpart;
        float4 s = p4[(size_t)rb * 64 + tid];
        #pragma unroll
        for (int hh = 1; hh < KSPLIT; ++hh) {
            const float4 q = p4[(size_t)hh * TPART_F4_STRIDE + rb * 64 + tid];
            s.x += q.x; s.y += q.y; s.z += q.z; s.w += q.w;
        }
        t_s4[tid] = s;
    }

    const int c4 = cb * 256 + tid;        // float4 column index
    const float4* Bt4 = (const float4*)Bt;
    float4 bv[16];
    #pragma unroll
    for (int r = 0; r < 16; ++r)
        bv[r] = Bt4[r * NF + c4];         // 1KB contiguous per instr (L2)

    __syncthreads();

    float4* out4 = (float4*)out;
    const float* t_s = (const float*)t_s4;

    #pragma unroll
    for (int row = 0; row < 16; ++row) {
        float4 tq[4];
        #pragma unroll
        for (int q = 0; q < 4; ++q)
            tq[q] = t_s4[row * 4 + q];    // LDS broadcast
        float4 o = {0.f, 0.f, 0.f, 0.f};
        #pragma unroll
        for (int r = 0; r < 16; ++r) {
            const float4 tv4 = tq[r >> 2];
            const float tv = ((r & 3) == 0) ? tv4.x :
                             ((r & 3) == 1) ? tv4.y :
                             ((r & 3) == 2) ? tv4.z : tv4.w;
            o.x = fmaf(tv, bv[r].x, o.x);
            o.y = fmaf(tv, bv[r].y, o.y);
            o.z = fmaf(tv, bv[r].z, o.z);
            o.w = fmaf(tv, bv[r].w, o.w);
        }
        out4[(size_t)(rb * 16 + row) * NF + c4] = o;
    }
    (void)t_s;
}

extern "C" void kernel_launch(void* const* d_in, const int* in_sizes, int n_in,
                              void* d_out, int out_size, void* d_ws, size_t ws_size,
                              hipStream_t stream) {
    const float* x = (const float*)d_in[0];            // [4,2048,4096]
    const float* B = (const float*)d_in[1];            // [4096,16]
    const float* A = (const float*)d_in[2];            // [16,4096]
    float* out = (float*)d_out;                        // [4,2048,4096]

    float* Bt    = (float*)d_ws;                       // [16][4096]  256 KB
    float* tpart = Bt + 16 * N_DIM;                    // [4][8192][16]  2 MB

    transpose_B<<<(N_DIM * 16) / 256, 256, 0, stream>>>(B, Bt);
    lora_xat<<<(M_ROWS / 16) * KSPLIT, 256, 0, stream>>>(x, A, tpart);
    lora_tb<<<(M_ROWS / 16) * (N_DIM / 1024), 256, 0, stream>>>(tpart, Bt, out);
}